// Round 3
// baseline (134.509 us; speedup 1.0000x reference)
//
#include <hip/hip_runtime.h>
#include <hip/hip_bf16.h>

#define B_    32
#define NBB_  16
#define C_    1024
#define NROI  512
#define KCONV 9216
#define SCALE_ (1.0f/16.0f)
#define EPS_  1e-5f

using f32x4  = __attribute__((ext_vector_type(4))) float;
using bf16x8 = __attribute__((ext_vector_type(8))) short;

__device__ __forceinline__ unsigned f2bf(float f) {
  union { float f; unsigned u; } x; x.f = f;
  unsigned r = x.u + 0x7fffu + ((x.u >> 16) & 1u);   // RNE
  return r >> 16;
}

__device__ __forceinline__ float hat_int(float t) {
  t = fminf(fmaxf(t, -1.f), 1.f);
  return t + 0.5f - 0.5f * t * fabsf(t);
}

__device__ __forceinline__ void glds16(const void* g, void* l) {
  __builtin_amdgcn_global_load_lds((const __attribute__((address_space(1))) void*)g,
                                   (__attribute__((address_space(3))) void*)l, 16, 0, 0);
}

// ---------------- K0: per-ROI separable integral weights (1/area folded into Wx)
__global__ __launch_bounds__(32) void prep_rois(const float* __restrict__ bbox,
                                                float* __restrict__ wy,
                                                float* __restrict__ wx) {
  int r = blockIdx.x;
  float4 bb = ((const float4*)bbox)[r];
  float x1 = bb.x * SCALE_, y1 = bb.y * SCALE_;
  float x2 = (bb.x + bb.z) * SCALE_, y2 = (bb.y + bb.w) * SCALE_;
  float bw = (x2 - x1) / 3.f, bh = (y2 - y1) / 3.f;
  float area = fmaxf(bw * bh, 0.f);
  float inv = area > 0.f ? 1.f / fmaxf(area, 1e-12f) : 0.f;
  int i = threadIdx.x;
  if (i < 22) {
    float fi = (float)i;
#pragma unroll
    for (int q = 0; q < 3; ++q) {
      float sy = y1 + q * bh;
      wy[r*66 + q*22 + i] = hat_int(sy + bh - fi) - hat_int(sy - fi);
      float sx = x1 + q * bw;
      wx[r*66 + q*22 + i] = (hat_int(sx + bw - fi) - hat_int(sx - fi)) * inv;
    }
  }
}

// ---------------- K1: fp32 -> bf16 converter (linear, for MLP weights)
__global__ __launch_bounds__(256) void cvt_bf16(const float* __restrict__ src,
                                                unsigned short* __restrict__ dst, int n8) {
  int i = blockIdx.x * 256 + threadIdx.x;
  if (i >= n8) return;
  float4 a = ((const float4*)src)[2*i];
  float4 b = ((const float4*)src)[2*i + 1];
  uint4 pk;
  pk.x = f2bf(a.x) | (f2bf(a.y) << 16);
  pk.y = f2bf(a.z) | (f2bf(a.w) << 16);
  pk.z = f2bf(b.x) | (f2bf(b.y) << 16);
  pk.w = f2bf(b.z) | (f2bf(b.w) << 16);
  ((uint4*)dst)[i] = pk;
}

// ---------------- K1b: conv_w [o][c][qp] fp32 -> Wfb[o][qp*1024 + c] bf16 (transpose+cvt)
__global__ __launch_bounds__(256) void convw_t(const float* __restrict__ cw,
                                               unsigned short* __restrict__ out) {
  __shared__ float T[9][260];
  int o = blockIdx.x, cc = blockIdx.y;   // cc: 256-channel chunk 0..3
  int tid = threadIdx.x;
  const float* src = cw + (size_t)o * 9216 + (size_t)cc * 2304;
  for (int i = tid; i < 576; i += 256) {
    float4 v = ((const float4*)src)[i];
    int e = i * 4;
#pragma unroll
    for (int j = 0; j < 4; ++j) {
      int ee = e + j;
      int c = ee / 9, qp = ee - c * 9;
      T[qp][c] = ((const float*)&v)[j];
    }
  }
  __syncthreads();
  unsigned short* dst = out + (size_t)o * 9216 + cc * 256 + tid;
#pragma unroll
  for (int qp = 0; qp < 9; ++qp) dst[qp * 1024] = (unsigned short)f2bf(T[qp][tid]);
}

// ---------------- K2a: build W2d[b][(n,qp)][k=h*22+w] = wy[n,q,h]*wx[n,p,w], bf16, K padded to 512
__global__ __launch_bounds__(192) void w2d_build(const float* __restrict__ wy,
                                                 const float* __restrict__ wx,
                                                 unsigned short* __restrict__ W2d) {
  __shared__ float wyS[1056], wxS[1056];
  int b = blockIdx.x, tid = threadIdx.x;
  for (int i = tid; i < 1056; i += 192) { wyS[i] = wy[(size_t)b*1056 + i]; wxS[i] = wx[(size_t)b*1056 + i]; }
  __syncthreads();
  if (tid < 144) {
    int n = tid / 9, qp = tid - n*9, q = qp / 3, p = qp - q*3;
    const float* wyp = wyS + n*66 + q*22;
    const float* wxp = wxS + n*66 + p*22;
    unsigned short* out = W2d + ((size_t)b*144 + tid) * 512;
    for (int h = 0; h < 22; ++h) {
      float yv = wyp[h];
      int kb = h * 22;
#pragma unroll
      for (int w = 0; w < 22; w += 2) {
        unsigned pk = f2bf(yv * wxp[w]) | (f2bf(yv * wxp[w+1]) << 16);
        *(unsigned*)&out[kb + w] = pk;          // kb+w even -> 4B aligned
      }
    }
    for (int k = 484; k < 512; k += 2) *(unsigned*)&out[k] = 0u;
  }
}

// ---------------- K2b: pooling GEMM per batch. X[(b*16+n)][qp*1024+c] = W2d[b] . feat[b]^T
// Block = (nch: 64-channel chunk, b); 384 thr = 6 waves (3 wm x 2 wn); M=144, N=64, K=512(484).
__global__ __launch_bounds__(384) void pool_gemm(const float* __restrict__ feat,
                                                 const unsigned short* __restrict__ W2d,
                                                 unsigned short* __restrict__ X) {
  __shared__ __align__(16) unsigned short As[144 * 72];   // 20736 B, row stride 72 elems
  __shared__ __align__(16) unsigned short Bs[64 * 72];    //  9216 B
  int tid = threadIdx.x;
  int nch = blockIdx.x, b = blockIdx.y;
  int lane = tid & 63, wid = tid >> 6;
  int wm = wid >> 1, wn = wid & 1;            // wm 0..2 (48 rows), wn 0..1 (32 cols)
  int l15 = lane & 15, kg = lane >> 4;
  const unsigned short* w2b = W2d + (size_t)b * 144 * 512;
  const float* fb = feat + ((size_t)b * C_ + (size_t)nch * 64) * 484;
  f32x4 acc[3][2] = {};

  for (int s = 0; s < 8; ++s) {
    __syncthreads();                           // protect LDS vs prev-iter reads
    // stage A (W2d bf16): 1152 uint4
#pragma unroll
    for (int t = 0; t < 3; ++t) {
      int i = tid + t * 384;
      int row = i >> 3, slot = i & 7;
      uint4 v = *(const uint4*)(w2b + (size_t)row * 512 + s * 64 + slot * 8);
      *(uint4*)&As[row * 72 + slot * 8] = v;
    }
    // stage B (feat fp32 -> bf16): 1024 float4 sources; tail step masked (k>=484 -> 0)
    for (int i = tid; i < 1024; i += 384) {
      int c = i >> 4, f4 = i & 15;
      float4 v;
      if (s < 7 || f4 <= 8) v = *(const float4*)(fb + (size_t)c * 484 + s * 64 + f4 * 4);
      else v = make_float4(0.f, 0.f, 0.f, 0.f);
      uint2 pk;
      pk.x = f2bf(v.x) | (f2bf(v.y) << 16);
      pk.y = f2bf(v.z) | (f2bf(v.w) << 16);
      *(uint2*)&Bs[c * 72 + f4 * 4] = pk;
    }
    __syncthreads();

    bf16x8 af[3][2], bf[2][2];
#pragma unroll
    for (int fm = 0; fm < 3; ++fm)
#pragma unroll
      for (int kk = 0; kk < 2; ++kk)
        af[fm][kk] = *(const bf16x8*)&As[(wm*48 + fm*16 + l15) * 72 + kk*32 + kg*8];
#pragma unroll
    for (int fn = 0; fn < 2; ++fn)
#pragma unroll
      for (int kk = 0; kk < 2; ++kk)
        bf[fn][kk] = *(const bf16x8*)&Bs[(wn*32 + fn*16 + l15) * 72 + kk*32 + kg*8];
#pragma unroll
    for (int fm = 0; fm < 3; ++fm)
#pragma unroll
      for (int fn = 0; fn < 2; ++fn) {
        acc[fm][fn] = __builtin_amdgcn_mfma_f32_16x16x32_bf16(af[fm][0], bf[fn][0], acc[fm][fn], 0, 0, 0);
        acc[fm][fn] = __builtin_amdgcn_mfma_f32_16x16x32_bf16(af[fm][1], bf[fn][1], acc[fm][fn], 0, 0, 0);
      }
  }

  // C-write: row m=(n,qp) -> X[b*16+n][qp*1024 + nch*64 + col], coalesced bf16
#pragma unroll
  for (int fm = 0; fm < 3; ++fm)
#pragma unroll
    for (int r = 0; r < 4; ++r) {
      int m = wm*48 + fm*16 + kg*4 + r;
      int n = m / 9, qp = m - n*9;
      size_t base = ((size_t)(b*16 + n)) * KCONV + (size_t)qp * 1024 + (size_t)nch * 64;
#pragma unroll
      for (int fn = 0; fn < 2; ++fn)
        X[base + wn*32 + fn*16 + l15] = (unsigned short)f2bf(acc[fm][fn][r]);
    }
}

// ---------------- K3: 128x128 NT GEMM, bf16 MFMA, global_load_lds + dbuf + XOR swizzle, split-K.
__global__ __launch_bounds__(256) void gemm128(const unsigned short* __restrict__ A,
                                               const unsigned short* __restrict__ Bm,
                                               float* __restrict__ Cp,
                                               int M, int N, int K, int kChunk) {
  __shared__ __align__(16) unsigned short As[2][4096];
  __shared__ __align__(16) unsigned short Bs[2][4096];
  int tid = threadIdx.x;
  int lane = tid & 63, wid = tid >> 6;
  int wm = wid >> 1, wn = wid & 1;
  int l15 = lane & 15, kg = lane >> 4;
  int nt = blockIdx.x, mt = blockIdx.y, z = blockIdx.z;
  int kbeg = z * kChunk;
  int steps = kChunk / 32;

  int row0 = tid >> 2, row1 = 64 + row0;
  int slot = tid & 3;
  int s0 = slot ^ ((row0 >> 1) & 3);
  int s1 = slot ^ ((row1 >> 1) & 3);
  const unsigned short* ga0 = A  + (size_t)(mt*128 + row0) * K + kbeg + s0*8;
  const unsigned short* ga1 = A  + (size_t)(mt*128 + row1) * K + kbeg + s1*8;
  const unsigned short* gb0 = Bm + (size_t)(nt*128 + row0) * K + kbeg + s0*8;
  const unsigned short* gb1 = Bm + (size_t)(nt*128 + row1) * K + kbeg + s1*8;
  int wbyte = wid * 1024;

  f32x4 acc[4][4] = {};
  int cur = 0;

#define ISSUE(buf, s) do { int ko = (s) * 32; \
    glds16(ga0 + ko, (char*)&As[(buf)][0] + wbyte); \
    glds16(ga1 + ko, (char*)&As[(buf)][0] + 4096 + wbyte); \
    glds16(gb0 + ko, (char*)&Bs[(buf)][0] + wbyte); \
    glds16(gb1 + ko, (char*)&Bs[(buf)][0] + 4096 + wbyte); } while (0)

  ISSUE(0, 0);
  for (int s = 0; s < steps; ++s) {
    __syncthreads();
    if (s + 1 < steps) ISSUE(cur ^ 1, s + 1);
    bf16x8 af[4], bfr[4];
#pragma unroll
    for (int fm = 0; fm < 4; ++fm) {
      int fr = wm*64 + fm*16 + l15;
      af[fm] = *(const bf16x8*)&As[cur][fr*32 + ((kg ^ ((fr >> 1) & 3)) << 3)];
    }
#pragma unroll
    for (int fn = 0; fn < 4; ++fn) {
      int fr = wn*64 + fn*16 + l15;
      bfr[fn] = *(const bf16x8*)&Bs[cur][fr*32 + ((kg ^ ((fr >> 1) & 3)) << 3)];
    }
#pragma unroll
    for (int fm = 0; fm < 4; ++fm)
#pragma unroll
      for (int fn = 0; fn < 4; ++fn)
        acc[fm][fn] = __builtin_amdgcn_mfma_f32_16x16x32_bf16(af[fm], bfr[fn], acc[fm][fn], 0, 0, 0);
    cur ^= 1;
  }
#undef ISSUE

  float* cp = Cp + ((size_t)z * M + (size_t)mt * 128) * N + (size_t)nt * 128;
#pragma unroll
  for (int fm = 0; fm < 4; ++fm)
#pragma unroll
    for (int fn = 0; fn < 4; ++fn)
#pragma unroll
      for (int r = 0; r < 4; ++r) {
        int row = wm*64 + fm*16 + kg*4 + r;
        int col = wn*64 + fn*16 + l15;
        cp[(size_t)row * N + col] = acc[fm][fn][r];
      }
}

// ---------------- K3b: 64x64 NT GEMM (MLP sizes)
__global__ __launch_bounds__(256) void gemm_nt(const unsigned short* __restrict__ A,
                                               const unsigned short* __restrict__ Bm,
                                               float* __restrict__ Cp,
                                               int M, int N, int K, int kChunk) {
  __shared__ __align__(16) unsigned short As[64][40];
  __shared__ __align__(16) unsigned short Bs[64][40];
  int tid = threadIdx.x;
  int lane = tid & 63, wid = tid >> 6;
  int wm = wid >> 1, wn = wid & 1;
  int l15 = lane & 15, kg = lane >> 4;
  int nt = blockIdx.x, mt = blockIdx.y, z = blockIdx.z;
  int kbeg = z * kChunk;
  int kend = kbeg + kChunk; if (kend > K) kend = K;
  int srow = tid >> 2, sseg = tid & 3;
  const unsigned short* aG = A  + (size_t)(mt*64 + srow) * K + sseg * 8;
  const unsigned short* bG = Bm + (size_t)(nt*64 + srow) * K + sseg * 8;
  f32x4 acc[2][2] = {};

  for (int k0 = kbeg; k0 < kend; k0 += 32) {
    uint4 av = *(const uint4*)(aG + k0);
    uint4 bv = *(const uint4*)(bG + k0);
    __syncthreads();
    *(uint4*)&As[srow][sseg*8] = av;
    *(uint4*)&Bs[srow][sseg*8] = bv;
    __syncthreads();
    bf16x8 a0 = *(const bf16x8*)&As[wm*32 +      l15][kg*8];
    bf16x8 a1 = *(const bf16x8*)&As[wm*32 + 16 + l15][kg*8];
    bf16x8 b0 = *(const bf16x8*)&Bs[wn*32 +      l15][kg*8];
    bf16x8 b1 = *(const bf16x8*)&Bs[wn*32 + 16 + l15][kg*8];
    acc[0][0] = __builtin_amdgcn_mfma_f32_16x16x32_bf16(a0, b0, acc[0][0], 0, 0, 0);
    acc[0][1] = __builtin_amdgcn_mfma_f32_16x16x32_bf16(a0, b1, acc[0][1], 0, 0, 0);
    acc[1][0] = __builtin_amdgcn_mfma_f32_16x16x32_bf16(a1, b0, acc[1][0], 0, 0, 0);
    acc[1][1] = __builtin_amdgcn_mfma_f32_16x16x32_bf16(a1, b1, acc[1][1], 0, 0, 0);
  }

  float* cp = Cp + ((size_t)z * M + (size_t)mt * 64) * N + (size_t)nt * 64;
#pragma unroll
  for (int fm = 0; fm < 2; ++fm)
#pragma unroll
    for (int fn = 0; fn < 2; ++fn)
#pragma unroll
      for (int r = 0; r < 4; ++r) {
        int row = wm*32 + fm*16 + kg*4 + r;
        int col = wn*32 + fn*16 + l15;
        cp[(size_t)row * N + col] = acc[fm][fn][r];
      }
}

// ---------------- K4: split-K reduce + epilogue
template<int MODE>
__global__ __launch_bounds__(256) void epi(const float* __restrict__ Cp, int SK, int MN4, int N,
                                           const float* __restrict__ bias,
                                           const float* __restrict__ g,
                                           const float* __restrict__ be,
                                           const float* __restrict__ mu,
                                           const float* __restrict__ var,
                                           unsigned short* __restrict__ outb,
                                           float* __restrict__ outf) {
  int i = blockIdx.x * 256 + threadIdx.x;
  if (i >= MN4) return;
  float4 s = ((const float4*)Cp)[i];
  for (int z = 1; z < SK; ++z) {
    float4 t = ((const float4*)Cp)[(size_t)z * MN4 + i];
    s.x += t.x; s.y += t.y; s.z += t.z; s.w += t.w;
  }
  int n0 = (i * 4) % N;
  float v[4] = {s.x, s.y, s.z, s.w};
  if (MODE == 0) {
    unsigned o[4];
#pragma unroll
    for (int j = 0; j < 4; ++j) {
      int n = n0 + j;
      float sc = g[n] * rsqrtf(var[n] + EPS_);
      float t = (v[j] + bias[n] - mu[n]) * sc + be[n];
      o[j] = f2bf(fmaxf(t, 0.f));
    }
    uint2 pk; pk.x = o[0] | (o[1] << 16); pk.y = o[2] | (o[3] << 16);
    *(uint2*)&outb[(size_t)i * 4] = pk;
  } else if (MODE == 1) {
    unsigned o[4];
#pragma unroll
    for (int j = 0; j < 4; ++j) o[j] = f2bf(fmaxf(v[j] + bias[n0 + j], 0.f));
    uint2 pk; pk.x = o[0] | (o[1] << 16); pk.y = o[2] | (o[3] << 16);
    *(uint2*)&outb[(size_t)i * 4] = pk;
  } else {
    float4 o;
    o.x = v[0] + bias[n0];     o.y = v[1] + bias[n0 + 1];
    o.z = v[2] + bias[n0 + 2]; o.w = v[3] + bias[n0 + 3];
    ((float4*)outf)[i] = o;
  }
}

extern "C" void kernel_launch(void* const* d_in, const int* in_sizes, int n_in,
                              void* d_out, int out_size, void* d_ws, size_t ws_size,
                              hipStream_t stream) {
  const float* feat   = (const float*)d_in[0];
  const float* bbox   = (const float*)d_in[1];
  const float* conv_w = (const float*)d_in[2];
  const float* conv_b = (const float*)d_in[3];
  const float* gamma  = (const float*)d_in[4];
  const float* beta   = (const float*)d_in[5];
  const float* mean   = (const float*)d_in[6];
  const float* var    = (const float*)d_in[7];
  const float* w1     = (const float*)d_in[8];
  const float* b1     = (const float*)d_in[9];
  const float* w2     = (const float*)d_in[10];
  const float* b2     = (const float*)d_in[11];
  const float* w3     = (const float*)d_in[12];
  const float* b3     = (const float*)d_in[13];

  char* ws = (char*)d_ws;
  // region0 [0, 4988928): wy,wx,W2d — dead after pool_gemm; H0/H1/H2 overlay later.
  float*          wy  = (float*)(ws);                       //  135168 B
  float*          wx  = (float*)(ws + 135168);              //  135168 B
  unsigned short* W2d = (unsigned short*)(ws + 270336);     // 4718592 B [32][144][512]
  unsigned short* H0  = (unsigned short*)(ws);              // 1048576 B (overlay)
  unsigned short* H1  = (unsigned short*)(ws + 1048576);    //  524288 B (overlay)
  unsigned short* H2  = (unsigned short*)(ws + 1572864);    //  524288 B (overlay)
  unsigned short* Xb  = (unsigned short*)(ws + 4988928);    // 9437184 B [512][9216]
  unsigned short* Wfb = (unsigned short*)(ws + 14426112);   // 18874368 B [1024][9216] (k'=qp*1024+c)
  unsigned short* w1b = (unsigned short*)(ws + 33300480);   // 1048576 B
  unsigned short* w2b = (unsigned short*)(ws + 34349056);   //  524288 B
  unsigned short* w3b = (unsigned short*)(ws + 34873344);   //  524288 B
  float*          part= (float*)(ws + 35397632);            // 12582912 B [6][512][1024] f32
                                                            // total 47980544 B

  prep_rois<<<NROI, 32, 0, stream>>>(bbox, wy, wx);
  w2d_build<<<32, 192, 0, stream>>>(wy, wx, W2d);
  convw_t<<<dim3(1024, 4), 256, 0, stream>>>(conv_w, Wfb);
  cvt_bf16<<<(65536 + 255) / 256, 256, 0, stream>>>(w1, w1b, 65536);
  cvt_bf16<<<(32768 + 255) / 256, 256, 0, stream>>>(w2, w2b, 32768);
  cvt_bf16<<<(32768 + 255) / 256, 256, 0, stream>>>(w3, w3b, 32768);

  // pooling GEMM: per-b, M=144, N=1024 (16 chunks of 64), K=512
  pool_gemm<<<dim3(16, 32), 384, 0, stream>>>(feat, W2d, Xb);

  // conv GEMM: [512,9216] x [1024,9216]^T, 128^2 tiles, SK=6 -> 192 blocks
  gemm128<<<dim3(8, 4, 6), 256, 0, stream>>>(Xb, Wfb, part, 512, 1024, 9216, 1536);
  epi<0><<<(131072 + 255) / 256, 256, 0, stream>>>(part, 6, 131072, 1024,
      conv_b, gamma, beta, mean, var, H0, nullptr);

  // MLP1: [512,1024] x [512,1024]^T, SK=4
  gemm_nt<<<dim3(8, 8, 4), 256, 0, stream>>>(H0, w1b, part, 512, 512, 1024, 256);
  epi<1><<<(65536 + 255) / 256, 256, 0, stream>>>(part, 4, 65536, 512,
      b1, nullptr, nullptr, nullptr, nullptr, H1, nullptr);

  // MLP2: [512,512] x [512,512]^T, SK=4
  gemm_nt<<<dim3(8, 8, 4), 256, 0, stream>>>(H1, w2b, part, 512, 512, 512, 128);
  epi<1><<<(65536 + 255) / 256, 256, 0, stream>>>(part, 4, 65536, 512,
      b2, nullptr, nullptr, nullptr, nullptr, H2, nullptr);

  // MLP3: [512,512] x [512,512]^T, SK=4, fp32 out
  gemm_nt<<<dim3(8, 8, 4), 256, 0, stream>>>(H2, w3b, part, 512, 512, 512, 128);
  epi<2><<<(65536 + 255) / 256, 256, 0, stream>>>(part, 4, 65536, 512,
      b3, nullptr, nullptr, nullptr, nullptr, nullptr, (float*)d_out);
}

// Round 4
// 126.782 us; speedup vs baseline: 1.0609x; 1.0609x over previous
//
#include <hip/hip_runtime.h>
#include <hip/hip_bf16.h>

#define B_    32
#define NBB_  16
#define C_    1024
#define NROI  512
#define KCONV 9216
#define SCALE_ (1.0f/16.0f)
#define EPS_  1e-5f

using f32x4  = __attribute__((ext_vector_type(4))) float;
using bf16x8 = __attribute__((ext_vector_type(8))) short;

__device__ __forceinline__ unsigned f2bf(float f) {
  union { float f; unsigned u; } x; x.f = f;
  unsigned r = x.u + 0x7fffu + ((x.u >> 16) & 1u);   // RNE
  return r >> 16;
}

// packed RNE f32x2 -> bf16x2 (v_cvt_pk path via HIP intrinsic)
__device__ __forceinline__ unsigned pk_bf16(float lo, float hi) {
  __hip_bfloat162 h = __float22bfloat162_rn(make_float2(lo, hi));
  return *reinterpret_cast<unsigned*>(&h);
}

__device__ __forceinline__ float hat_int(float t) {
  t = fminf(fmaxf(t, -1.f), 1.f);
  return t + 0.5f - 0.5f * t * fabsf(t);
}

__device__ __forceinline__ void glds16(const void* g, void* l) {
  __builtin_amdgcn_global_load_lds((const __attribute__((address_space(1))) void*)g,
                                   (__attribute__((address_space(3))) void*)l, 16, 0, 0);
}

// ---------------- K0: fused ROI weights + W2d build.
// Block = batch b (32 blocks, 192 thr). W2d[b][(n,qp)][k=h*22+w] = wy[n,q,h]*wx[n,p,w], bf16, K pad 512.
__global__ __launch_bounds__(192) void prep_w2d(const float* __restrict__ bbox,
                                                unsigned short* __restrict__ W2d) {
  __shared__ float wyS[16*66], wxS[16*66];
  int b = blockIdx.x, tid = threadIdx.x;
  for (int t = tid; t < 352; t += 192) {
    int n = t / 22, i = t - n * 22;
    float4 bb = ((const float4*)bbox)[b*16 + n];
    float x1 = bb.x * SCALE_, y1 = bb.y * SCALE_;
    float x2 = (bb.x + bb.z) * SCALE_, y2 = (bb.y + bb.w) * SCALE_;
    float bw = (x2 - x1) / 3.f, bh = (y2 - y1) / 3.f;
    float area = fmaxf(bw * bh, 0.f);
    float inv = area > 0.f ? 1.f / fmaxf(area, 1e-12f) : 0.f;
    float fi = (float)i;
#pragma unroll
    for (int q = 0; q < 3; ++q) {
      float sy = y1 + q * bh;
      wyS[n*66 + q*22 + i] = hat_int(sy + bh - fi) - hat_int(sy - fi);
      float sx = x1 + q * bw;
      wxS[n*66 + q*22 + i] = (hat_int(sx + bw - fi) - hat_int(sx - fi)) * inv;
    }
  }
  __syncthreads();
  if (tid < 144) {
    int n = tid / 9, qp = tid - n*9, q = qp / 3, p = qp - q*3;
    const float* wyp = wyS + n*66 + q*22;
    const float* wxp = wxS + n*66 + p*22;
    unsigned short* out = W2d + ((size_t)b*144 + tid) * 512;
    for (int h = 0; h < 22; ++h) {
      float yv = wyp[h];
      int kb = h * 22;
#pragma unroll
      for (int w = 0; w < 22; w += 2)
        *(unsigned*)&out[kb + w] = pk_bf16(yv * wxp[w], yv * wxp[w+1]);
    }
#pragma unroll
    for (int k = 484; k < 512; k += 2) *(unsigned*)&out[k] = 0u;
  }
}

// ---------------- K1: fp32 -> bf16 converter (linear, MLP weights)
__global__ __launch_bounds__(256) void cvt_bf16(const float* __restrict__ src,
                                                unsigned short* __restrict__ dst, int n8) {
  int i = blockIdx.x * 256 + threadIdx.x;
  if (i >= n8) return;
  float4 a = ((const float4*)src)[2*i];
  float4 b = ((const float4*)src)[2*i + 1];
  uint4 pk;
  pk.x = pk_bf16(a.x, a.y); pk.y = pk_bf16(a.z, a.w);
  pk.z = pk_bf16(b.x, b.y); pk.w = pk_bf16(b.z, b.w);
  ((uint4*)dst)[i] = pk;
}

// ---------------- K1b: conv_w [o][c][qp] fp32 -> Wfb[o][qp*1024 + c] bf16. Block per o, coalesced.
__global__ __launch_bounds__(256) void convw_t(const float* __restrict__ cw,
                                               unsigned short* __restrict__ out) {
  __shared__ unsigned short T[9][1028];     // 18504 B
  int o = blockIdx.x, tid = threadIdx.x;
  const float4* src = (const float4*)(cw + (size_t)o * 9216);
#pragma unroll
  for (int it = 0; it < 9; ++it) {
    int i = tid + it * 256;                 // 2304 float4 total
    float4 v = src[i];
    int e = i * 4;
    {
      int c = e / 9, qp = e - c * 9;
      T[qp][c] = (unsigned short)f2bf(v.x);
    }
    { int ee = e+1; int c = ee / 9, qp = ee - c * 9; T[qp][c] = (unsigned short)f2bf(v.y); }
    { int ee = e+2; int c = ee / 9, qp = ee - c * 9; T[qp][c] = (unsigned short)f2bf(v.z); }
    { int ee = e+3; int c = ee / 9, qp = ee - c * 9; T[qp][c] = (unsigned short)f2bf(v.w); }
  }
  __syncthreads();
  unsigned short* dst = out + (size_t)o * 9216;
#pragma unroll
  for (int qp = 0; qp < 9; ++qp) {
    uint2 w = *(const uint2*)&T[qp][tid * 4];
    ((uint2*)(dst + qp * 1024))[tid] = w;
  }
}

// ---------------- K2: pooling GEMM. X[(b*16+n)][qp*1024+c] = W2d[b] . feat[b]^T
// Block = (nch 64-ch chunk, b); 384 thr = 6 waves (3wm x 2wn). M=144, N=64, K=512(484).
// A-fragments direct from global (L2-resident); B staged reg->LDS with T14 prefetch.
__global__ __launch_bounds__(384) void pool_gemm(const float* __restrict__ feat,
                                                 const unsigned short* __restrict__ W2d,
                                                 unsigned short* __restrict__ X) {
  __shared__ __align__(16) unsigned short Bs[64 * 72];   // 9216 B
  int tid = threadIdx.x;
  int nch = blockIdx.x, b = blockIdx.y;
  int lane = tid & 63, wid = tid >> 6;
  int wm = wid >> 1, wn = wid & 1;
  int l15 = lane & 15, kg = lane >> 4;
  const unsigned short* w2b = W2d + (size_t)b * 144 * 512;
  const float* fb = feat + ((size_t)b * C_ + (size_t)nch * 64) * 484;
  f32x4 acc[3][2] = {};

  int c0 = tid >> 4,        f40 = tid & 15;
  int i1 = tid + 384;  int c1 = i1 >> 4, f41 = i1 & 15;
  int i2 = tid + 768;  bool has2 = i2 < 1024; int c2 = i2 >> 4, f42 = i2 & 15;
  float4 bR0, bR1, bR2;

#define LOADB(s) do { \
    bR0 = (((s) < 7 || f40 <= 8) ? *(const float4*)(fb + (size_t)c0*484 + (s)*64 + f40*4) : make_float4(0,0,0,0)); \
    bR1 = (((s) < 7 || f41 <= 8) ? *(const float4*)(fb + (size_t)c1*484 + (s)*64 + f41*4) : make_float4(0,0,0,0)); \
    if (has2) bR2 = (((s) < 7 || f42 <= 8) ? *(const float4*)(fb + (size_t)c2*484 + (s)*64 + f42*4) : make_float4(0,0,0,0)); \
  } while (0)

  LOADB(0);
#pragma unroll
  for (int s = 0; s < 8; ++s) {
    __syncthreads();                       // prev step's Bs reads complete
    {
      uint2 p0; p0.x = pk_bf16(bR0.x, bR0.y); p0.y = pk_bf16(bR0.z, bR0.w);
      *(uint2*)&Bs[c0*72 + f40*4] = p0;
      uint2 p1; p1.x = pk_bf16(bR1.x, bR1.y); p1.y = pk_bf16(bR1.z, bR1.w);
      *(uint2*)&Bs[c1*72 + f41*4] = p1;
      if (has2) {
        uint2 p2; p2.x = pk_bf16(bR2.x, bR2.y); p2.y = pk_bf16(bR2.z, bR2.w);
        *(uint2*)&Bs[c2*72 + f42*4] = p2;
      }
    }
    if (s < 7) LOADB(s + 1);               // T14: issue next-step loads before compute
    __syncthreads();                       // Bs ready

    bf16x8 af[3][2], bf[2][2];
#pragma unroll
    for (int fm = 0; fm < 3; ++fm)
#pragma unroll
      for (int kk = 0; kk < 2; ++kk)
        af[fm][kk] = *(const bf16x8*)(w2b + (size_t)(wm*48 + fm*16 + l15) * 512 + s*64 + kk*32 + kg*8);
#pragma unroll
    for (int fn = 0; fn < 2; ++fn)
#pragma unroll
      for (int kk = 0; kk < 2; ++kk)
        bf[fn][kk] = *(const bf16x8*)&Bs[(wn*32 + fn*16 + l15) * 72 + kk*32 + kg*8];
#pragma unroll
    for (int fm = 0; fm < 3; ++fm)
#pragma unroll
      for (int fn = 0; fn < 2; ++fn) {
        acc[fm][fn] = __builtin_amdgcn_mfma_f32_16x16x32_bf16(af[fm][0], bf[fn][0], acc[fm][fn], 0, 0, 0);
        acc[fm][fn] = __builtin_amdgcn_mfma_f32_16x16x32_bf16(af[fm][1], bf[fn][1], acc[fm][fn], 0, 0, 0);
      }
  }
#undef LOADB

#pragma unroll
  for (int fm = 0; fm < 3; ++fm)
#pragma unroll
    for (int r = 0; r < 4; ++r) {
      int m = wm*48 + fm*16 + kg*4 + r;
      int n = m / 9, qp = m - n*9;
      size_t base = ((size_t)(b*16 + n)) * KCONV + (size_t)qp * 1024 + (size_t)nch * 64;
#pragma unroll
      for (int fn = 0; fn < 2; ++fn)
        X[base + wn*32 + fn*16 + l15] = (unsigned short)f2bf(acc[fm][fn][r]);
    }
}

// ---------------- K3: 128x128 NT GEMM, bf16 MFMA, global_load_lds + dbuf + XOR swizzle, split-K.
__global__ __launch_bounds__(256) void gemm128(const unsigned short* __restrict__ A,
                                               const unsigned short* __restrict__ Bm,
                                               float* __restrict__ Cp,
                                               int M, int N, int K, int kChunk) {
  __shared__ __align__(16) unsigned short As[2][4096];
  __shared__ __align__(16) unsigned short Bs[2][4096];
  int tid = threadIdx.x;
  int lane = tid & 63, wid = tid >> 6;
  int wm = wid >> 1, wn = wid & 1;
  int l15 = lane & 15, kg = lane >> 4;
  int nt = blockIdx.x, mt = blockIdx.y, z = blockIdx.z;
  int kbeg = z * kChunk;
  int steps = kChunk / 32;

  int row0 = tid >> 2, row1 = 64 + row0;
  int slot = tid & 3;
  int s0 = slot ^ ((row0 >> 1) & 3);
  int s1 = slot ^ ((row1 >> 1) & 3);
  const unsigned short* ga0 = A  + (size_t)(mt*128 + row0) * K + kbeg + s0*8;
  const unsigned short* ga1 = A  + (size_t)(mt*128 + row1) * K + kbeg + s1*8;
  const unsigned short* gb0 = Bm + (size_t)(nt*128 + row0) * K + kbeg + s0*8;
  const unsigned short* gb1 = Bm + (size_t)(nt*128 + row1) * K + kbeg + s1*8;
  int wbyte = wid * 1024;

  f32x4 acc[4][4] = {};
  int cur = 0;

#define ISSUE(buf, s) do { int ko = (s) * 32; \
    glds16(ga0 + ko, (char*)&As[(buf)][0] + wbyte); \
    glds16(ga1 + ko, (char*)&As[(buf)][0] + 4096 + wbyte); \
    glds16(gb0 + ko, (char*)&Bs[(buf)][0] + wbyte); \
    glds16(gb1 + ko, (char*)&Bs[(buf)][0] + 4096 + wbyte); } while (0)

  ISSUE(0, 0);
  for (int s = 0; s < steps; ++s) {
    __syncthreads();
    if (s + 1 < steps) ISSUE(cur ^ 1, s + 1);
    bf16x8 af[4], bfr[4];
#pragma unroll
    for (int fm = 0; fm < 4; ++fm) {
      int fr = wm*64 + fm*16 + l15;
      af[fm] = *(const bf16x8*)&As[cur][fr*32 + ((kg ^ ((fr >> 1) & 3)) << 3)];
    }
#pragma unroll
    for (int fn = 0; fn < 4; ++fn) {
      int fr = wn*64 + fn*16 + l15;
      bfr[fn] = *(const bf16x8*)&Bs[cur][fr*32 + ((kg ^ ((fr >> 1) & 3)) << 3)];
    }
#pragma unroll
    for (int fm = 0; fm < 4; ++fm)
#pragma unroll
      for (int fn = 0; fn < 4; ++fn)
        acc[fm][fn] = __builtin_amdgcn_mfma_f32_16x16x32_bf16(af[fm], bfr[fn], acc[fm][fn], 0, 0, 0);
    cur ^= 1;
  }
#undef ISSUE

  float* cp = Cp + ((size_t)z * M + (size_t)mt * 128) * N + (size_t)nt * 128;
#pragma unroll
  for (int fm = 0; fm < 4; ++fm)
#pragma unroll
    for (int fn = 0; fn < 4; ++fn)
#pragma unroll
      for (int r = 0; r < 4; ++r) {
        int row = wm*64 + fm*16 + kg*4 + r;
        int col = wn*64 + fn*16 + l15;
        cp[(size_t)row * N + col] = acc[fm][fn][r];
      }
}

// ---------------- K3b: 64x64 NT GEMM (MLP sizes)
__global__ __launch_bounds__(256) void gemm_nt(const unsigned short* __restrict__ A,
                                               const unsigned short* __restrict__ Bm,
                                               float* __restrict__ Cp,
                                               int M, int N, int K, int kChunk) {
  __shared__ __align__(16) unsigned short As[64][40];
  __shared__ __align__(16) unsigned short Bs[64][40];
  int tid = threadIdx.x;
  int lane = tid & 63, wid = tid >> 6;
  int wm = wid >> 1, wn = wid & 1;
  int l15 = lane & 15, kg = lane >> 4;
  int nt = blockIdx.x, mt = blockIdx.y, z = blockIdx.z;
  int kbeg = z * kChunk;
  int kend = kbeg + kChunk; if (kend > K) kend = K;
  int srow = tid >> 2, sseg = tid & 3;
  const unsigned short* aG = A  + (size_t)(mt*64 + srow) * K + sseg * 8;
  const unsigned short* bG = Bm + (size_t)(nt*64 + srow) * K + sseg * 8;
  f32x4 acc[2][2] = {};

  for (int k0 = kbeg; k0 < kend; k0 += 32) {
    uint4 av = *(const uint4*)(aG + k0);
    uint4 bv = *(const uint4*)(bG + k0);
    __syncthreads();
    *(uint4*)&As[srow][sseg*8] = av;
    *(uint4*)&Bs[srow][sseg*8] = bv;
    __syncthreads();
    bf16x8 a0 = *(const bf16x8*)&As[wm*32 +      l15][kg*8];
    bf16x8 a1 = *(const bf16x8*)&As[wm*32 + 16 + l15][kg*8];
    bf16x8 b0 = *(const bf16x8*)&Bs[wn*32 +      l15][kg*8];
    bf16x8 b1 = *(const bf16x8*)&Bs[wn*32 + 16 + l15][kg*8];
    acc[0][0] = __builtin_amdgcn_mfma_f32_16x16x32_bf16(a0, b0, acc[0][0], 0, 0, 0);
    acc[0][1] = __builtin_amdgcn_mfma_f32_16x16x32_bf16(a0, b1, acc[0][1], 0, 0, 0);
    acc[1][0] = __builtin_amdgcn_mfma_f32_16x16x32_bf16(a1, b0, acc[1][0], 0, 0, 0);
    acc[1][1] = __builtin_amdgcn_mfma_f32_16x16x32_bf16(a1, b1, acc[1][1], 0, 0, 0);
  }

  float* cp = Cp + ((size_t)z * M + (size_t)mt * 64) * N + (size_t)nt * 64;
#pragma unroll
  for (int fm = 0; fm < 2; ++fm)
#pragma unroll
    for (int fn = 0; fn < 2; ++fn)
#pragma unroll
      for (int r = 0; r < 4; ++r) {
        int row = wm*32 + fm*16 + kg*4 + r;
        int col = wn*32 + fn*16 + l15;
        cp[(size_t)row * N + col] = acc[fm][fn][r];
      }
}

// ---------------- K4: split-K reduce + epilogue
template<int MODE>
__global__ __launch_bounds__(256) void epi(const float* __restrict__ Cp, int SK, int MN4, int N,
                                           const float* __restrict__ bias,
                                           const float* __restrict__ g,
                                           const float* __restrict__ be,
                                           const float* __restrict__ mu,
                                           const float* __restrict__ var,
                                           unsigned short* __restrict__ outb,
                                           float* __restrict__ outf) {
  int i = blockIdx.x * 256 + threadIdx.x;
  if (i >= MN4) return;
  float4 s = ((const float4*)Cp)[i];
  for (int z = 1; z < SK; ++z) {
    float4 t = ((const float4*)Cp)[(size_t)z * MN4 + i];
    s.x += t.x; s.y += t.y; s.z += t.z; s.w += t.w;
  }
  int n0 = (i * 4) % N;
  float v[4] = {s.x, s.y, s.z, s.w};
  if (MODE == 0) {
    float o[4];
#pragma unroll
    for (int j = 0; j < 4; ++j) {
      int n = n0 + j;
      float sc = g[n] * rsqrtf(var[n] + EPS_);
      o[j] = fmaxf((v[j] + bias[n] - mu[n]) * sc + be[n], 0.f);
    }
    uint2 pk; pk.x = pk_bf16(o[0], o[1]); pk.y = pk_bf16(o[2], o[3]);
    *(uint2*)&outb[(size_t)i * 4] = pk;
  } else if (MODE == 1) {
    uint2 pk;
    pk.x = pk_bf16(fmaxf(v[0] + bias[n0], 0.f),     fmaxf(v[1] + bias[n0+1], 0.f));
    pk.y = pk_bf16(fmaxf(v[2] + bias[n0+2], 0.f),   fmaxf(v[3] + bias[n0+3], 0.f));
    *(uint2*)&outb[(size_t)i * 4] = pk;
  } else {
    float4 o;
    o.x = v[0] + bias[n0];     o.y = v[1] + bias[n0 + 1];
    o.z = v[2] + bias[n0 + 2]; o.w = v[3] + bias[n0 + 3];
    ((float4*)outf)[i] = o;
  }
}

extern "C" void kernel_launch(void* const* d_in, const int* in_sizes, int n_in,
                              void* d_out, int out_size, void* d_ws, size_t ws_size,
                              hipStream_t stream) {
  const float* feat   = (const float*)d_in[0];
  const float* bbox   = (const float*)d_in[1];
  const float* conv_w = (const float*)d_in[2];
  const float* conv_b = (const float*)d_in[3];
  const float* gamma  = (const float*)d_in[4];
  const float* beta   = (const float*)d_in[5];
  const float* mean   = (const float*)d_in[6];
  const float* var    = (const float*)d_in[7];
  const float* w1     = (const float*)d_in[8];
  const float* b1     = (const float*)d_in[9];
  const float* w2     = (const float*)d_in[10];
  const float* b2     = (const float*)d_in[11];
  const float* w3     = (const float*)d_in[12];
  const float* b3     = (const float*)d_in[13];

  char* ws = (char*)d_ws;
  unsigned short* W2d = (unsigned short*)(ws);              //  4718592 B [32][144][512]
  unsigned short* Xb  = (unsigned short*)(ws + 4718592);    //  9437184 B [512][9216]
  unsigned short* Wfb = (unsigned short*)(ws + 14155776);   // 18874368 B [1024][9216] (k'=qp*1024+c)
  unsigned short* w1b = (unsigned short*)(ws + 33030144);   //  1048576 B
  unsigned short* w2b = (unsigned short*)(ws + 34078720);   //   524288 B
  unsigned short* w3b = (unsigned short*)(ws + 34603008);   //   524288 B
  float*          part= (float*)(ws + 35127296);            // 16777216 B [8][512][1024] f32
  unsigned short* H0  = (unsigned short*)(ws + 51904512);   //  1048576 B
  unsigned short* H1  = (unsigned short*)(ws + 52953088);   //   524288 B
  unsigned short* H2  = (unsigned short*)(ws + 53477376);   //   524288 B (total 54001664 B)

  prep_w2d<<<32, 192, 0, stream>>>(bbox, W2d);
  convw_t<<<1024, 256, 0, stream>>>(conv_w, Wfb);
  cvt_bf16<<<(65536 + 255) / 256, 256, 0, stream>>>(w1, w1b, 65536);
  cvt_bf16<<<(32768 + 255) / 256, 256, 0, stream>>>(w2, w2b, 32768);
  cvt_bf16<<<(32768 + 255) / 256, 256, 0, stream>>>(w3, w3b, 32768);

  // pooling GEMM: per-b, M=144, N=1024 (16 chunks of 64), K=512
  pool_gemm<<<dim3(16, 32), 384, 0, stream>>>(feat, W2d, Xb);

  // conv GEMM: [512,9216] x [1024,9216]^T, 128^2 tiles, SK=8 -> 256 blocks
  gemm128<<<dim3(8, 4, 8), 256, 0, stream>>>(Xb, Wfb, part, 512, 1024, 9216, 1152);
  epi<0><<<(131072 + 255) / 256, 256, 0, stream>>>(part, 8, 131072, 1024,
      conv_b, gamma, beta, mean, var, H0, nullptr);

  // MLP1: [512,1024] x [512,1024]^T, SK=4
  gemm_nt<<<dim3(8, 8, 4), 256, 0, stream>>>(H0, w1b, part, 512, 512, 1024, 256);
  epi<1><<<(65536 + 255) / 256, 256, 0, stream>>>(part, 4, 65536, 512,
      b1, nullptr, nullptr, nullptr, nullptr, H1, nullptr);

  // MLP2: [512,512] x [512,512]^T, SK=4
  gemm_nt<<<dim3(8, 8, 4), 256, 0, stream>>>(H1, w2b, part, 512, 512, 512, 128);
  epi<1><<<(65536 + 255) / 256, 256, 0, stream>>>(part, 4, 65536, 512,
      b2, nullptr, nullptr, nullptr, nullptr, H2, nullptr);

  // MLP3: [512,512] x [512,512]^T, SK=4, fp32 out
  gemm_nt<<<dim3(8, 8, 4), 256, 0, stream>>>(H2, w3b, part, 512, 512, 512, 128);
  epi<2><<<(65536 + 255) / 256, 256, 0, stream>>>(part, 4, 65536, 512,
      b3, nullptr, nullptr, nullptr, nullptr, nullptr, (float*)d_out);
}